// Round 1
// baseline (506.608 us; speedup 1.0000x reference)
//
#include <hip/hip_runtime.h>

#define I_F 8192
#define O_F 8192
#define NSPLIT 128
#define CHUNK (I_F / NSPLIT)   // 64 rows of i per block

// 3-level cndmask tree: select lut[q] from 8 values held in 2 float4 regs.
// Avoids dynamic register indexing (which would spill to scratch).
__device__ __forceinline__ float lut_sel(const float4& lo, const float4& hi, int q) {
    const bool b2 = (q & 4) != 0;
    const float s0 = b2 ? hi.x : lo.x;
    const float s1 = b2 ? hi.y : lo.y;
    const float s2 = b2 ? hi.z : lo.z;
    const float s3 = b2 ? hi.w : lo.w;
    const bool b1 = (q & 2) != 0;
    const float t0 = b1 ? s2 : s0;
    const float t1 = b1 ? s3 : s1;
    return (q & 1) ? t1 : t0;
}

// Zero the 8x8192 output and build xT[i][b] = x[b][i] (32B contiguous per i)
// so the dense kernel's per-i x read is one uniform 32B scalar load.
__global__ __launch_bounds__(256) void prolog_kernel(const float* __restrict__ x,
                                                     float* __restrict__ xT,
                                                     float* __restrict__ out) {
    const int t = blockIdx.x * 256 + threadIdx.x;   // 0..65535
    out[t] = 0.0f;
    if (t < I_F) {
        float4 lo, hi;
        lo.x = x[0 * I_F + t];
        lo.y = x[1 * I_F + t];
        lo.z = x[2 * I_F + t];
        lo.w = x[3 * I_F + t];
        hi.x = x[4 * I_F + t];
        hi.y = x[5 * I_F + t];
        hi.z = x[6 * I_F + t];
        hi.w = x[7 * I_F + t];
        ((float4*)xT)[t * 2]     = lo;
        ((float4*)xT)[t * 2 + 1] = hi;
    }
}

// Dense: y[b,o] += sum_i x[b,i] * lut[o, qidx[i,o]]
// Thread owns 4 consecutive columns (int4 qidx loads, 16B/lane coalesced).
// grid = (O_F/1024 colTiles, NSPLIT iChunks), block = 256.
__global__ __launch_bounds__(256) void dense_kernel(const int* __restrict__ qidx,
                                                    const float* __restrict__ lut,
                                                    const float* __restrict__ xT,
                                                    float* __restrict__ out) {
    const int col0 = (blockIdx.x * 256 + threadIdx.x) * 4;
    const int i0 = blockIdx.y * CHUNK;

    // Preload the 4 columns' LUT rows: 8 f32 each -> 2 float4 regs/col.
    float4 lA[4], lB[4];
#pragma unroll
    for (int c = 0; c < 4; ++c) {
        const float4* p = (const float4*)(lut + (size_t)(col0 + c) * 8);
        lA[c] = p[0];
        lB[c] = p[1];
    }

    float acc[4][8];
#pragma unroll
    for (int c = 0; c < 4; ++c)
#pragma unroll
        for (int b = 0; b < 8; ++b) acc[c][b] = 0.0f;

    const int4*   qp = (const int4*)(qidx + (size_t)i0 * O_F + col0);
    const float4* xp = (const float4*)(xT + (size_t)i0 * 8);

#pragma unroll 4
    for (int ii = 0; ii < CHUNK; ++ii) {
        const int4   q   = qp[(size_t)ii * (O_F / 4)];
        const float4 xlo = xp[ii * 2];       // uniform -> s_load
        const float4 xhi = xp[ii * 2 + 1];
#pragma unroll
        for (int c = 0; c < 4; ++c) {
            const int qc = (c == 0) ? q.x : (c == 1) ? q.y : (c == 2) ? q.z : q.w;
            const float w = lut_sel(lA[c], lB[c], qc);
            acc[c][0] += xlo.x * w;
            acc[c][1] += xlo.y * w;
            acc[c][2] += xlo.z * w;
            acc[c][3] += xlo.w * w;
            acc[c][4] += xhi.x * w;
            acc[c][5] += xhi.y * w;
            acc[c][6] += xhi.z * w;
            acc[c][7] += xhi.w * w;
        }
    }

#pragma unroll
    for (int b = 0; b < 8; ++b)
#pragma unroll
        for (int c = 0; c < 4; ++c)
            atomicAdd(&out[(size_t)b * O_F + col0 + c], acc[c][b]);
}

// Sparse: one wave per output row o; 128 nnz -> 2 per lane; gather from
// L2-resident xT; butterfly-reduce 8 per-b partials; lane 0 atomics.
__global__ __launch_bounds__(256) void sparse_kernel(const int* __restrict__ rows,
                                                     const int* __restrict__ cols,
                                                     const float* __restrict__ vals,
                                                     const float* __restrict__ xT,
                                                     float* __restrict__ out) {
    const int wave = threadIdx.x >> 6;
    const int lane = threadIdx.x & 63;
    const int o = blockIdx.x * 4 + wave;
    const int r0 = rows[o];
    const int r1 = rows[o + 1];

    float acc[8];
#pragma unroll
    for (int b = 0; b < 8; ++b) acc[b] = 0.0f;

    for (int k = r0 + lane; k < r1; k += 64) {
        const int   col = cols[k];
        const float v   = vals[k];
        const float4* xp = (const float4*)(xT + (size_t)col * 8);
        const float4 xlo = xp[0];
        const float4 xhi = xp[1];
        acc[0] += v * xlo.x;
        acc[1] += v * xlo.y;
        acc[2] += v * xlo.z;
        acc[3] += v * xlo.w;
        acc[4] += v * xhi.x;
        acc[5] += v * xhi.y;
        acc[6] += v * xhi.z;
        acc[7] += v * xhi.w;
    }

#pragma unroll
    for (int s = 1; s < 64; s <<= 1)
#pragma unroll
        for (int b = 0; b < 8; ++b) acc[b] += __shfl_xor(acc[b], s, 64);

    if (lane == 0) {
#pragma unroll
        for (int b = 0; b < 8; ++b) atomicAdd(&out[(size_t)b * O_F + o], acc[b]);
    }
}

extern "C" void kernel_launch(void* const* d_in, const int* in_sizes, int n_in,
                              void* d_out, int out_size, void* d_ws, size_t ws_size,
                              hipStream_t stream) {
    const float* x    = (const float*)d_in[0];
    const int*   qidx = (const int*)d_in[1];
    const float* lut  = (const float*)d_in[2];
    const int*   rows = (const int*)d_in[3];
    const int*   cols = (const int*)d_in[4];
    const float* vals = (const float*)d_in[5];
    float* out = (float*)d_out;
    float* xT  = (float*)d_ws;   // 8192*8 f32 = 256 KB

    prolog_kernel<<<256, 256, 0, stream>>>(x, xT, out);
    dense_kernel<<<dim3(O_F / 1024, NSPLIT), 256, 0, stream>>>(qidx, lut, xT, out);
    sparse_kernel<<<O_F / 4, 256, 0, stream>>>(rows, cols, vals, xT, out);
}

// Round 4
// 405.711 us; speedup vs baseline: 1.2487x; 1.2487x over previous
//
#include <hip/hip_runtime.h>

#define I_F 8192
#define O_F 8192

// 3-level cndmask tree: select lut[q] from 8 values held in 2 float4 regs.
// Avoids dynamic register indexing (which would go to scratch).
__device__ __forceinline__ float lut_sel(const float4& lo, const float4& hi, int q) {
    const bool b2 = (q & 4) != 0;
    const float s0 = b2 ? hi.x : lo.x;
    const float s1 = b2 ? hi.y : lo.y;
    const float s2 = b2 ? hi.z : lo.z;
    const float s3 = b2 ? hi.w : lo.w;
    const bool b1 = (q & 2) != 0;
    const float t0 = b1 ? s2 : s0;
    const float t1 = b1 ? s3 : s1;
    return (q & 1) ? t1 : t0;
}

// Build xT[i][b] = x[b][i] (32B contiguous per i) so the dense kernel's
// per-i x read is one uniform 32B scalar load. grid = 32 x 256.
__global__ __launch_bounds__(256) void prolog_kernel(const float* __restrict__ x,
                                                     float* __restrict__ xT) {
    const int t = blockIdx.x * 256 + threadIdx.x;   // 0..8191
    float4 lo, hi;
    lo.x = x[0 * I_F + t];
    lo.y = x[1 * I_F + t];
    lo.z = x[2 * I_F + t];
    lo.w = x[3 * I_F + t];
    hi.x = x[4 * I_F + t];
    hi.y = x[5 * I_F + t];
    hi.z = x[6 * I_F + t];
    hi.w = x[7 * I_F + t];
    ((float4*)xT)[t * 2]     = lo;
    ((float4*)xT)[t * 2 + 1] = hi;
}

// Dense partial: P[split][b][o] = sum_{i in chunk} x[b,i] * lut[o, qidx[i,o]]
// Thread owns 4 consecutive columns (int4 qidx loads, 16B/lane coalesced).
// grid = (O_F/1024, nsplit), block = 256. NO atomics: plain float4 stores.
__global__ __launch_bounds__(256) void dense_kernel(const int* __restrict__ qidx,
                                                    const float* __restrict__ lut,
                                                    const float* __restrict__ xT,
                                                    float* __restrict__ P,
                                                    int chunk) {
    const int col0 = (blockIdx.x * 256 + threadIdx.x) * 4;
    const int i0 = blockIdx.y * chunk;

    // Preload the 4 columns' LUT rows: 8 f32 each -> 2 float4 regs/col.
    float4 lA[4], lB[4];
#pragma unroll
    for (int c = 0; c < 4; ++c) {
        const float4* p = (const float4*)(lut + (size_t)(col0 + c) * 8);
        lA[c] = p[0];
        lB[c] = p[1];
    }

    float acc[4][8];
#pragma unroll
    for (int c = 0; c < 4; ++c)
#pragma unroll
        for (int b = 0; b < 8; ++b) acc[c][b] = 0.0f;

    const int4*   qp = (const int4*)(qidx + (size_t)i0 * O_F + col0);
    const float4* xp = (const float4*)(xT + (size_t)i0 * 8);

#pragma unroll 4
    for (int ii = 0; ii < chunk; ++ii) {
        const int4   q   = qp[(size_t)ii * (O_F / 4)];
        const float4 xlo = xp[ii * 2];       // uniform -> scalar load
        const float4 xhi = xp[ii * 2 + 1];
#pragma unroll
        for (int c = 0; c < 4; ++c) {
            const int qc = (c == 0) ? q.x : (c == 1) ? q.y : (c == 2) ? q.z : q.w;
            const float w = lut_sel(lA[c], lB[c], qc);
            acc[c][0] += xlo.x * w;
            acc[c][1] += xlo.y * w;
            acc[c][2] += xlo.z * w;
            acc[c][3] += xlo.w * w;
            acc[c][4] += xhi.x * w;
            acc[c][5] += xhi.y * w;
            acc[c][6] += xhi.z * w;
            acc[c][7] += xhi.w * w;
        }
    }

    // P layout: [split][b][O_F]; per b one float4 covering the 4 owned cols.
    float* Pb = P + ((size_t)blockIdx.y * 8) * O_F + col0;
#pragma unroll
    for (int b = 0; b < 8; ++b) {
        float4 v = make_float4(acc[0][b], acc[1][b], acc[2][b], acc[3][b]);
        *(float4*)(Pb + (size_t)b * O_F) = v;
    }
}

// Sparse: one wave per output row o; 128 nnz -> 2 per lane; gather from
// L2-resident xT; butterfly-reduce; lane 0 stores 8 values to sp. NO atomics.
__global__ __launch_bounds__(256) void sparse_kernel(const int* __restrict__ rows,
                                                     const int* __restrict__ cols,
                                                     const float* __restrict__ vals,
                                                     const float* __restrict__ xT,
                                                     float* __restrict__ sp) {
    const int wave = threadIdx.x >> 6;
    const int lane = threadIdx.x & 63;
    const int o = blockIdx.x * 4 + wave;
    const int r0 = rows[o];
    const int r1 = rows[o + 1];

    float acc[8];
#pragma unroll
    for (int b = 0; b < 8; ++b) acc[b] = 0.0f;

    for (int k = r0 + lane; k < r1; k += 64) {
        const int   col = cols[k];
        const float v   = vals[k];
        const float4* xp = (const float4*)(xT + (size_t)col * 8);
        const float4 xlo = xp[0];
        const float4 xhi = xp[1];
        acc[0] += v * xlo.x;
        acc[1] += v * xlo.y;
        acc[2] += v * xlo.z;
        acc[3] += v * xlo.w;
        acc[4] += v * xhi.x;
        acc[5] += v * xhi.y;
        acc[6] += v * xhi.z;
        acc[7] += v * xhi.w;
    }

#pragma unroll
    for (int s = 1; s < 64; s <<= 1)
#pragma unroll
        for (int b = 0; b < 8; ++b) acc[b] += __shfl_xor(acc[b], s, 64);

    if (lane == 0) {
#pragma unroll
        for (int b = 0; b < 8; ++b) sp[(size_t)b * O_F + o] = acc[b];
    }
}

// out[t] = sp[t] + sum_s P[s][t]  (t over 8*O_F elems, float4-vectorized).
// grid = 64 x 256.
__global__ __launch_bounds__(256) void reduce_kernel(const float* __restrict__ P,
                                                     const float* __restrict__ sp,
                                                     float* __restrict__ out,
                                                     int nsplit) {
    const int t4 = blockIdx.x * 256 + threadIdx.x;   // 0..16383 (float4 units)
    float4 s = ((const float4*)sp)[t4];
#pragma unroll 4
    for (int k = 0; k < nsplit; ++k) {
        const float4 p = ((const float4*)P)[(size_t)k * (8 * O_F / 4) + t4];
        s.x += p.x; s.y += p.y; s.z += p.z; s.w += p.w;
    }
    ((float4*)out)[t4] = s;
}

extern "C" void kernel_launch(void* const* d_in, const int* in_sizes, int n_in,
                              void* d_out, int out_size, void* d_ws, size_t ws_size,
                              hipStream_t stream) {
    const float* x    = (const float*)d_in[0];
    const int*   qidx = (const int*)d_in[1];
    const float* lut  = (const float*)d_in[2];
    const int*   rows = (const int*)d_in[3];
    const int*   cols = (const int*)d_in[4];
    const float* vals = (const float*)d_in[5];
    float* out = (float*)d_out;

    // Workspace layout: xT (256 KB) | sp (256 KB) | P (nsplit * 256 KB)
    float* xT = (float*)d_ws;
    float* sp = xT + (size_t)I_F * 8;
    float* P  = sp + (size_t)O_F * 8;

    // Pick nsplit to fit the workspace (ladder 128 -> 2).
    int nsplit = 128;
    const size_t fixed = (size_t)(I_F * 8 + O_F * 8) * sizeof(float);
    while (nsplit > 2 &&
           fixed + (size_t)nsplit * O_F * 8 * sizeof(float) > ws_size)
        nsplit >>= 1;
    const int chunk = I_F / nsplit;

    prolog_kernel<<<I_F / 256, 256, 0, stream>>>(x, xT);
    dense_kernel<<<dim3(O_F / 1024, nsplit), 256, 0, stream>>>(qidx, lut, xT, P, chunk);
    sparse_kernel<<<O_F / 4, 256, 0, stream>>>(rows, cols, vals, xT, sp);
    reduce_kernel<<<(8 * O_F / 4) / 256, 256, 0, stream>>>(P, sp, out, nsplit);
}

// Round 5
// 400.657 us; speedup vs baseline: 1.2644x; 1.0126x over previous
//
#include <hip/hip_runtime.h>

#define I_F 8192
#define O_F 8192
#define NSPLIT 64
#define CHUNK (I_F / NSPLIT)   // 128 i-rows per block

// 3-level cndmask tree: select lut[q] from 8 values held in 2 float4 regs.
// Avoids dynamic register indexing (which would go to scratch).
__device__ __forceinline__ float lut_sel(const float4& lo, const float4& hi, int q) {
    const bool b2 = (q & 4) != 0;
    const float s0 = b2 ? hi.x : lo.x;
    const float s1 = b2 ? hi.y : lo.y;
    const float s2 = b2 ? hi.z : lo.z;
    const float s3 = b2 ? hi.w : lo.w;
    const bool b1 = (q & 2) != 0;
    const float t0 = b1 ? s2 : s0;
    const float t1 = b1 ? s3 : s1;
    return (q & 1) ? t1 : t0;
}

// Build xT[i][b] = x[b][i] (32B contiguous per i). grid = 32 x 256.
__global__ __launch_bounds__(256) void prolog_kernel(const float* __restrict__ x,
                                                     float* __restrict__ xT) {
    const int t = blockIdx.x * 256 + threadIdx.x;   // 0..8191
    float4 lo, hi;
    lo.x = x[0 * I_F + t];
    lo.y = x[1 * I_F + t];
    lo.z = x[2 * I_F + t];
    lo.w = x[3 * I_F + t];
    hi.x = x[4 * I_F + t];
    hi.y = x[5 * I_F + t];
    hi.z = x[6 * I_F + t];
    hi.w = x[7 * I_F + t];
    ((float4*)xT)[t * 2]     = lo;
    ((float4*)xT)[t * 2 + 1] = hi;
}

// Dense partial: P[split][b][o] = sum_{i in chunk} x[b,i] * lut[o, qidx[i,o]]
// x-chunk staged in LDS (4 KB) so the inner loop has exactly ONE vmem op
// (the coalesced int4 qidx load). grid = (8, NSPLIT), block = 256.
__global__ __launch_bounds__(256) void dense_kernel(const int* __restrict__ qidx,
                                                    const float* __restrict__ lut,
                                                    const float* __restrict__ xT,
                                                    float* __restrict__ P) {
    __shared__ float4 xs[CHUNK][2];    // xs[ii] = {x[0..3][i0+ii], x[4..7][i0+ii]}

    const int tid = threadIdx.x;
    const int col0 = (blockIdx.x * 256 + tid) * 4;
    const int i0 = blockIdx.y * CHUNK;

    // Stage x-chunk: CHUNK*2 = 256 float4s, one per thread, fully coalesced.
    ((float4*)xs)[tid] = ((const float4*)(xT + (size_t)i0 * 8))[tid];

    // Preload the 4 columns' LUT rows: 8 f32 each -> 2 float4 regs/col.
    float4 lA[4], lB[4];
#pragma unroll
    for (int c = 0; c < 4; ++c) {
        const float4* p = (const float4*)(lut + (size_t)(col0 + c) * 8);
        lA[c] = p[0];
        lB[c] = p[1];
    }

    float acc[4][8];
#pragma unroll
    for (int c = 0; c < 4; ++c)
#pragma unroll
        for (int b = 0; b < 8; ++b) acc[c][b] = 0.0f;

    __syncthreads();

    const int4* qp = (const int4*)(qidx + (size_t)i0 * O_F + col0);

#pragma unroll 8
    for (int ii = 0; ii < CHUNK; ++ii) {
        const int4   q   = qp[(size_t)ii * (O_F / 4)];
        const float4 xlo = xs[ii][0];      // LDS broadcast (lgkmcnt, not vmcnt)
        const float4 xhi = xs[ii][1];
#pragma unroll
        for (int c = 0; c < 4; ++c) {
            const int qc = (c == 0) ? q.x : (c == 1) ? q.y : (c == 2) ? q.z : q.w;
            const float w = lut_sel(lA[c], lB[c], qc);
            acc[c][0] += xlo.x * w;
            acc[c][1] += xlo.y * w;
            acc[c][2] += xlo.z * w;
            acc[c][3] += xlo.w * w;
            acc[c][4] += xhi.x * w;
            acc[c][5] += xhi.y * w;
            acc[c][6] += xhi.z * w;
            acc[c][7] += xhi.w * w;
        }
    }

    // P layout: [split][b][O_F]; per b one float4 covering the 4 owned cols.
    float* Pb = P + ((size_t)blockIdx.y * 8) * O_F + col0;
#pragma unroll
    for (int b = 0; b < 8; ++b) {
        float4 v = make_float4(acc[0][b], acc[1][b], acc[2][b], acc[3][b]);
        *(float4*)(Pb + (size_t)b * O_F) = v;
    }
}

// Sparse: one wave per output row o; 128 nnz -> 2 per lane; gather from
// L2-resident xT; butterfly-reduce; lane 0 stores 8 values to sp. NO atomics.
__global__ __launch_bounds__(256) void sparse_kernel(const int* __restrict__ rows,
                                                     const int* __restrict__ cols,
                                                     const float* __restrict__ vals,
                                                     const float* __restrict__ xT,
                                                     float* __restrict__ sp) {
    const int wave = threadIdx.x >> 6;
    const int lane = threadIdx.x & 63;
    const int o = blockIdx.x * 4 + wave;
    const int r0 = rows[o];
    const int r1 = rows[o + 1];

    float acc[8];
#pragma unroll
    for (int b = 0; b < 8; ++b) acc[b] = 0.0f;

    for (int k = r0 + lane; k < r1; k += 64) {
        const int   col = cols[k];
        const float v   = vals[k];
        const float4* xp = (const float4*)(xT + (size_t)col * 8);
        const float4 xlo = xp[0];
        const float4 xhi = xp[1];
        acc[0] += v * xlo.x;
        acc[1] += v * xlo.y;
        acc[2] += v * xlo.z;
        acc[3] += v * xlo.w;
        acc[4] += v * xhi.x;
        acc[5] += v * xhi.y;
        acc[6] += v * xhi.z;
        acc[7] += v * xhi.w;
    }

#pragma unroll
    for (int s = 1; s < 64; s <<= 1)
#pragma unroll
        for (int b = 0; b < 8; ++b) acc[b] += __shfl_xor(acc[b], s, 64);

    if (lane == 0) {
#pragma unroll
        for (int b = 0; b < 8; ++b) sp[(size_t)b * O_F + o] = acc[b];
    }
}

// out[t] = sp[t] + sum_s P[s][t]  (t over 8*O_F elems, float4-vectorized).
// grid = 256 x 64 (one wave per CU; unroll-8 keeps 8 KB/wave in flight).
__global__ __launch_bounds__(64) void reduce_kernel(const float* __restrict__ P,
                                                    const float* __restrict__ sp,
                                                    float* __restrict__ out) {
    const int t4 = blockIdx.x * 64 + threadIdx.x;   // 0..16383 (float4 units)
    float4 s = ((const float4*)sp)[t4];
#pragma unroll 8
    for (int k = 0; k < NSPLIT; ++k) {
        const float4 p = ((const float4*)P)[(size_t)k * (8 * O_F / 4) + t4];
        s.x += p.x; s.y += p.y; s.z += p.z; s.w += p.w;
    }
    ((float4*)out)[t4] = s;
}

extern "C" void kernel_launch(void* const* d_in, const int* in_sizes, int n_in,
                              void* d_out, int out_size, void* d_ws, size_t ws_size,
                              hipStream_t stream) {
    const float* x    = (const float*)d_in[0];
    const int*   qidx = (const int*)d_in[1];
    const float* lut  = (const float*)d_in[2];
    const int*   rows = (const int*)d_in[3];
    const int*   cols = (const int*)d_in[4];
    const float* vals = (const float*)d_in[5];
    float* out = (float*)d_out;

    // Workspace layout: xT (256 KB) | sp (256 KB) | P (NSPLIT * 256 KB = 16 MB)
    float* xT = (float*)d_ws;
    float* sp = xT + (size_t)I_F * 8;
    float* P  = sp + (size_t)O_F * 8;

    prolog_kernel<<<I_F / 256, 256, 0, stream>>>(x, xT);
    dense_kernel<<<dim3(O_F / 1024, NSPLIT), 256, 0, stream>>>(qidx, lut, xT, P);
    sparse_kernel<<<O_F / 4, 256, 0, stream>>>(rows, cols, vals, xT, sp);
    reduce_kernel<<<(8 * O_F / 4) / 64, 64, 0, stream>>>(P, sp, out);
}

// Round 6
// 394.707 us; speedup vs baseline: 1.2835x; 1.0151x over previous
//
#include <hip/hip_runtime.h>

#define I_F 8192
#define O_F 8192
#define NSPLIT 128
#define CHUNK (I_F / NSPLIT)   // 64 i-rows per block

// 3-level cndmask tree: select lut[q] from 8 values held in 2 float4 regs.
// Avoids dynamic register indexing (which would go to scratch).
__device__ __forceinline__ float lut_sel(const float4& lo, const float4& hi, int q) {
    const bool b2 = (q & 4) != 0;
    const float s0 = b2 ? hi.x : lo.x;
    const float s1 = b2 ? hi.y : lo.y;
    const float s2 = b2 ? hi.z : lo.z;
    const float s3 = b2 ? hi.w : lo.w;
    const bool b1 = (q & 2) != 0;
    const float t0 = b1 ? s2 : s0;
    const float t1 = b1 ? s3 : s1;
    return (q & 1) ? t1 : t0;
}

// Build xT[i][b] = x[b][i] (32B contiguous per i). grid = 32 x 256.
__global__ __launch_bounds__(256) void prolog_kernel(const float* __restrict__ x,
                                                     float* __restrict__ xT) {
    const int t = blockIdx.x * 256 + threadIdx.x;   // 0..8191
    float4 lo, hi;
    lo.x = x[0 * I_F + t];
    lo.y = x[1 * I_F + t];
    lo.z = x[2 * I_F + t];
    lo.w = x[3 * I_F + t];
    hi.x = x[4 * I_F + t];
    hi.y = x[5 * I_F + t];
    hi.z = x[6 * I_F + t];
    hi.w = x[7 * I_F + t];
    ((float4*)xT)[t * 2]     = lo;
    ((float4*)xT)[t * 2 + 1] = hi;
}

// Dense partial: P[split][b][o] = sum_{i in chunk} x[b,i] * lut[o, qidx[i,o]]
// grid = (8, NSPLIT) = 1024 blocks -> 4 blocks/CU resident (16 waves/CU) for
// memory-level parallelism; launch_bounds(256,4) caps VGPR at 128 (no spill,
// ~100 live) so the residency is realized. Inner loop: ONE vmem op (int4).
__global__ __launch_bounds__(256, 4) void dense_kernel(const int* __restrict__ qidx,
                                                       const float* __restrict__ lut,
                                                       const float* __restrict__ xT,
                                                       float* __restrict__ P) {
    __shared__ float4 xs[CHUNK][2];    // xs[ii] = {x[0..3][i0+ii], x[4..7][i0+ii]}

    const int tid = threadIdx.x;
    const int col0 = (blockIdx.x * 256 + tid) * 4;
    const int i0 = blockIdx.y * CHUNK;

    // Stage x-chunk: CHUNK*2 = 128 float4s, coalesced.
    if (tid < CHUNK * 2)
        ((float4*)xs)[tid] = ((const float4*)(xT + (size_t)i0 * 8))[tid];

    // Preload the 4 columns' LUT rows: 8 f32 each -> 2 float4 regs/col.
    float4 lA[4], lB[4];
#pragma unroll
    for (int c = 0; c < 4; ++c) {
        const float4* p = (const float4*)(lut + (size_t)(col0 + c) * 8);
        lA[c] = p[0];
        lB[c] = p[1];
    }

    float acc[4][8];
#pragma unroll
    for (int c = 0; c < 4; ++c)
#pragma unroll
        for (int b = 0; b < 8; ++b) acc[c][b] = 0.0f;

    __syncthreads();

    const int4* qp = (const int4*)(qidx + (size_t)i0 * O_F + col0);

#pragma unroll 8
    for (int ii = 0; ii < CHUNK; ++ii) {
        const int4   q   = qp[(size_t)ii * (O_F / 4)];
        const float4 xlo = xs[ii][0];      // LDS broadcast (lgkmcnt, not vmcnt)
        const float4 xhi = xs[ii][1];
#pragma unroll
        for (int c = 0; c < 4; ++c) {
            const int qc = (c == 0) ? q.x : (c == 1) ? q.y : (c == 2) ? q.z : q.w;
            const float w = lut_sel(lA[c], lB[c], qc);
            acc[c][0] += xlo.x * w;
            acc[c][1] += xlo.y * w;
            acc[c][2] += xlo.z * w;
            acc[c][3] += xlo.w * w;
            acc[c][4] += xhi.x * w;
            acc[c][5] += xhi.y * w;
            acc[c][6] += xhi.z * w;
            acc[c][7] += xhi.w * w;
        }
    }

    // P layout: [split][b][O_F]; per b one float4 covering the 4 owned cols.
    float* Pb = P + ((size_t)blockIdx.y * 8) * O_F + col0;
#pragma unroll
    for (int b = 0; b < 8; ++b) {
        float4 v = make_float4(acc[0][b], acc[1][b], acc[2][b], acc[3][b]);
        *(float4*)(Pb + (size_t)b * O_F) = v;
    }
}

// Sparse: one wave per output row o; 128 nnz -> 2 per lane; gather from
// L2-resident xT; butterfly-reduce; lane 0 stores 8 values to sp. NO atomics.
__global__ __launch_bounds__(256) void sparse_kernel(const int* __restrict__ rows,
                                                     const int* __restrict__ cols,
                                                     const float* __restrict__ vals,
                                                     const float* __restrict__ xT,
                                                     float* __restrict__ sp) {
    const int wave = threadIdx.x >> 6;
    const int lane = threadIdx.x & 63;
    const int o = blockIdx.x * 4 + wave;
    const int r0 = rows[o];
    const int r1 = rows[o + 1];

    float acc[8];
#pragma unroll
    for (int b = 0; b < 8; ++b) acc[b] = 0.0f;

    for (int k = r0 + lane; k < r1; k += 64) {
        const int   col = cols[k];
        const float v   = vals[k];
        const float4* xp = (const float4*)(xT + (size_t)col * 8);
        const float4 xlo = xp[0];
        const float4 xhi = xp[1];
        acc[0] += v * xlo.x;
        acc[1] += v * xlo.y;
        acc[2] += v * xlo.z;
        acc[3] += v * xlo.w;
        acc[4] += v * xhi.x;
        acc[5] += v * xhi.y;
        acc[6] += v * xhi.z;
        acc[7] += v * xhi.w;
    }

#pragma unroll
    for (int s = 1; s < 64; s <<= 1)
#pragma unroll
        for (int b = 0; b < 8; ++b) acc[b] += __shfl_xor(acc[b], s, 64);

    if (lane == 0) {
#pragma unroll
        for (int b = 0; b < 8; ++b) sp[(size_t)b * O_F + o] = acc[b];
    }
}

// out[t] = sp[t] + sum_s P[s][t]  (t over 8*O_F elems, float4-vectorized).
// grid = 256 x 64 (one wave per CU; unroll-8 keeps 8 KB/wave in flight).
__global__ __launch_bounds__(64) void reduce_kernel(const float* __restrict__ P,
                                                    const float* __restrict__ sp,
                                                    float* __restrict__ out) {
    const int t4 = blockIdx.x * 64 + threadIdx.x;   // 0..16383 (float4 units)
    float4 s = ((const float4*)sp)[t4];
#pragma unroll 8
    for (int k = 0; k < NSPLIT; ++k) {
        const float4 p = ((const float4*)P)[(size_t)k * (8 * O_F / 4) + t4];
        s.x += p.x; s.y += p.y; s.z += p.z; s.w += p.w;
    }
    ((float4*)out)[t4] = s;
}

extern "C" void kernel_launch(void* const* d_in, const int* in_sizes, int n_in,
                              void* d_out, int out_size, void* d_ws, size_t ws_size,
                              hipStream_t stream) {
    const float* x    = (const float*)d_in[0];
    const int*   qidx = (const int*)d_in[1];
    const float* lut  = (const float*)d_in[2];
    const int*   rows = (const int*)d_in[3];
    const int*   cols = (const int*)d_in[4];
    const float* vals = (const float*)d_in[5];
    float* out = (float*)d_out;

    // Workspace layout: xT (256 KB) | sp (256 KB) | P (NSPLIT * 256 KB = 32 MB)
    float* xT = (float*)d_ws;
    float* sp = xT + (size_t)I_F * 8;
    float* P  = sp + (size_t)O_F * 8;

    prolog_kernel<<<I_F / 256, 256, 0, stream>>>(x, xT);
    dense_kernel<<<dim3(O_F / 1024, NSPLIT), 256, 0, stream>>>(qidx, lut, xT, P);
    sparse_kernel<<<O_F / 4, 256, 0, stream>>>(rows, cols, vals, xT, sp);
    reduce_kernel<<<(8 * O_F / 4) / 64, 64, 0, stream>>>(P, sp, out);
}

// Round 8
// 392.492 us; speedup vs baseline: 1.2907x; 1.0056x over previous
//
#include <hip/hip_runtime.h>

#define I_F 8192
#define O_F 8192
#define NSPLIT 128
#define CHUNK (I_F / NSPLIT)   // 64 i-rows per block
#define QBATCH 8               // qidx loads kept in flight per wave

// 3-level cndmask tree: select lut[q] from 8 values held in 2 float4 regs.
__device__ __forceinline__ float lut_sel(const float4& lo, const float4& hi, int q) {
    const bool b2 = (q & 4) != 0;
    const float s0 = b2 ? hi.x : lo.x;
    const float s1 = b2 ? hi.y : lo.y;
    const float s2 = b2 ? hi.z : lo.z;
    const float s3 = b2 ? hi.w : lo.w;
    const bool b1 = (q & 2) != 0;
    const float t0 = b1 ? s2 : s0;
    const float t1 = b1 ? s3 : s1;
    return (q & 1) ? t1 : t0;
}

// Build xT[i][b] = x[b][i] (32B contiguous per i). grid = 32 x 256.
__global__ __launch_bounds__(256) void prolog_kernel(const float* __restrict__ x,
                                                     float* __restrict__ xT) {
    const int t = blockIdx.x * 256 + threadIdx.x;   // 0..8191
    float4 lo, hi;
    lo.x = x[0 * I_F + t];
    lo.y = x[1 * I_F + t];
    lo.z = x[2 * I_F + t];
    lo.w = x[3 * I_F + t];
    hi.x = x[4 * I_F + t];
    hi.y = x[5 * I_F + t];
    hi.z = x[6 * I_F + t];
    hi.w = x[7 * I_F + t];
    ((float4*)xT)[t * 2]     = lo;
    ((float4*)xT)[t * 2 + 1] = hi;
}

// Dense partial: P[split][b][o] = sum_{i in chunk} x[b,i] * lut[o, qidx[i,o]]
// MLP fix: per outer step issue QBATCH int4 qidx loads into a static register
// array (8 outstanding per wave; pragma-unroll alone did NOT batch — R4==R5),
// then consume. 16 waves/CU resident (launch_bounds(256,4), VGPR<=128).
__global__ __launch_bounds__(256, 4) void dense_kernel(const int* __restrict__ qidx,
                                                       const float* __restrict__ lut,
                                                       const float* __restrict__ xT,
                                                       float* __restrict__ P) {
    __shared__ float4 xs[CHUNK][2];    // xs[ii] = {x[0..3][i0+ii], x[4..7][i0+ii]}

    const int tid = threadIdx.x;
    const int col0 = (blockIdx.x * 256 + tid) * 4;
    const int i0 = blockIdx.y * CHUNK;

    // Stage x-chunk: CHUNK*2 = 128 float4s, coalesced.
    if (tid < CHUNK * 2)
        ((float4*)xs)[tid] = ((const float4*)(xT + (size_t)i0 * 8))[tid];

    // Preload the 4 columns' LUT rows: 8 f32 each -> 2 float4 regs/col.
    float4 lA[4], lB[4];
#pragma unroll
    for (int c = 0; c < 4; ++c) {
        const float4* p = (const float4*)(lut + (size_t)(col0 + c) * 8);
        lA[c] = p[0];
        lB[c] = p[1];
    }

    float acc[4][8];
#pragma unroll
    for (int c = 0; c < 4; ++c)
#pragma unroll
        for (int b = 0; b < 8; ++b) acc[c][b] = 0.0f;

    __syncthreads();

    const int4* qp = (const int4*)(qidx + (size_t)i0 * O_F + col0);

    for (int t = 0; t < CHUNK; t += QBATCH) {
        // Phase A: issue all QBATCH loads (static indices -> registers,
        // back-to-back global_load_dwordx4, 8 outstanding on vmcnt).
        int4 qb[QBATCH];
#pragma unroll
        for (int k = 0; k < QBATCH; ++k)
            qb[k] = qp[(size_t)(t + k) * (O_F / 4)];

        // Phase B: consume (waits retire vmcnt incrementally).
#pragma unroll
        for (int k = 0; k < QBATCH; ++k) {
            const int4   q   = qb[k];
            const float4 xlo = xs[t + k][0];
            const float4 xhi = xs[t + k][1];
#pragma unroll
            for (int c = 0; c < 4; ++c) {
                const int qc = (c == 0) ? q.x : (c == 1) ? q.y : (c == 2) ? q.z : q.w;
                const float w = lut_sel(lA[c], lB[c], qc);
                acc[c][0] += xlo.x * w;
                acc[c][1] += xlo.y * w;
                acc[c][2] += xlo.z * w;
                acc[c][3] += xlo.w * w;
                acc[c][4] += xhi.x * w;
                acc[c][5] += xhi.y * w;
                acc[c][6] += xhi.z * w;
                acc[c][7] += xhi.w * w;
            }
        }
    }

    // P layout: [split][b][O_F]; per b one float4 covering the 4 owned cols.
    float* Pb = P + ((size_t)blockIdx.y * 8) * O_F + col0;
#pragma unroll
    for (int b = 0; b < 8; ++b) {
        float4 v = make_float4(acc[0][b], acc[1][b], acc[2][b], acc[3][b]);
        *(float4*)(Pb + (size_t)b * O_F) = v;
    }
}

// Sparse: one wave per output row o; 128 nnz -> 2 per lane; gather from
// L2-resident xT; butterfly-reduce; lane 0 stores 8 values to sp. NO atomics.
__global__ __launch_bounds__(256) void sparse_kernel(const int* __restrict__ rows,
                                                     const int* __restrict__ cols,
                                                     const float* __restrict__ vals,
                                                     const float* __restrict__ xT,
                                                     float* __restrict__ sp) {
    const int wave = threadIdx.x >> 6;
    const int lane = threadIdx.x & 63;
    const int o = blockIdx.x * 4 + wave;
    const int r0 = rows[o];
    const int r1 = rows[o + 1];

    float acc[8];
#pragma unroll
    for (int b = 0; b < 8; ++b) acc[b] = 0.0f;

    for (int k = r0 + lane; k < r1; k += 64) {
        const int   col = cols[k];
        const float v   = vals[k];
        const float4* xp = (const float4*)(xT + (size_t)col * 8);
        const float4 xlo = xp[0];
        const float4 xhi = xp[1];
        acc[0] += v * xlo.x;
        acc[1] += v * xlo.y;
        acc[2] += v * xlo.z;
        acc[3] += v * xlo.w;
        acc[4] += v * xhi.x;
        acc[5] += v * xhi.y;
        acc[6] += v * xhi.z;
        acc[7] += v * xhi.w;
    }

#pragma unroll
    for (int s = 1; s < 64; s <<= 1)
#pragma unroll
        for (int b = 0; b < 8; ++b) acc[b] += __shfl_xor(acc[b], s, 64);

    if (lane == 0) {
#pragma unroll
        for (int b = 0; b < 8; ++b) sp[(size_t)b * O_F + o] = acc[b];
    }
}

// out[t] = sp[t] + sum_s P[s][t]  (t over 8*O_F elems, float4-vectorized).
// grid = 256 x 64 (one wave per CU; unroll-8 keeps 8 KB/wave in flight).
__global__ __launch_bounds__(64) void reduce_kernel(const float* __restrict__ P,
                                                    const float* __restrict__ sp,
                                                    float* __restrict__ out) {
    const int t4 = blockIdx.x * 64 + threadIdx.x;   // 0..16383 (float4 units)
    float4 s = ((const float4*)sp)[t4];
#pragma unroll 8
    for (int k = 0; k < NSPLIT; ++k) {
        const float4 p = ((const float4*)P)[(size_t)k * (8 * O_F / 4) + t4];
        s.x += p.x; s.y += p.y; s.z += p.z; s.w += p.w;
    }
    ((float4*)out)[t4] = s;
}

extern "C" void kernel_launch(void* const* d_in, const int* in_sizes, int n_in,
                              void* d_out, int out_size, void* d_ws, size_t ws_size,
                              hipStream_t stream) {
    const float* x    = (const float*)d_in[0];
    const int*   qidx = (const int*)d_in[1];
    const float* lut  = (const float*)d_in[2];
    const int*   rows = (const int*)d_in[3];
    const int*   cols = (const int*)d_in[4];
    const float* vals = (const float*)d_in[5];
    float* out = (float*)d_out;

    // Workspace layout: xT (256 KB) | sp (256 KB) | P (NSPLIT * 256 KB = 32 MB)
    float* xT = (float*)d_ws;
    float* sp = xT + (size_t)I_F * 8;
    float* P  = sp + (size_t)O_F * 8;

    prolog_kernel<<<I_F / 256, 256, 0, stream>>>(x, xT);
    dense_kernel<<<dim3(O_F / 1024, NSPLIT), 256, 0, stream>>>(qidx, lut, xT, P);
    sparse_kernel<<<O_F / 4, 256, 0, stream>>>(rows, cols, vals, xT, sp);
    reduce_kernel<<<(8 * O_F / 4) / 64, 64, 0, stream>>>(P, sp, out);
}

// Round 9
// 392.030 us; speedup vs baseline: 1.2923x; 1.0012x over previous
//
#include <hip/hip_runtime.h>

#define I_F 8192
#define O_F 8192
#define NSPLIT 128
#define CHUNK (I_F / NSPLIT)   // 64 i-rows per block
#define QBATCH 4               // qidx loads in flight per wave

// 3-level cndmask tree: select lut[q] from 8 values held in 2 float4 regs.
__device__ __forceinline__ float lut_sel(const float4& lo, const float4& hi, int q) {
    const bool b2 = (q & 4) != 0;
    const float s0 = b2 ? hi.x : lo.x;
    const float s1 = b2 ? hi.y : lo.y;
    const float s2 = b2 ? hi.z : lo.z;
    const float s3 = b2 ? hi.w : lo.w;
    const bool b1 = (q & 2) != 0;
    const float t0 = b1 ? s2 : s0;
    const float t1 = b1 ? s3 : s1;
    return (q & 1) ? t1 : t0;
}

// Build xT[i][b] = x[b][i] (32B contiguous per i). grid = 32 x 256.
__global__ __launch_bounds__(256) void prolog_kernel(const float* __restrict__ x,
                                                     float* __restrict__ xT) {
    const int t = blockIdx.x * 256 + threadIdx.x;   // 0..8191
    float4 lo, hi;
    lo.x = x[0 * I_F + t];
    lo.y = x[1 * I_F + t];
    lo.z = x[2 * I_F + t];
    lo.w = x[3 * I_F + t];
    hi.x = x[4 * I_F + t];
    hi.y = x[5 * I_F + t];
    hi.z = x[6 * I_F + t];
    hi.w = x[7 * I_F + t];
    ((float4*)xT)[t * 2]     = lo;
    ((float4*)xT)[t * 2 + 1] = hi;
}

// Dense partial: P[split][b][o] = sum_{i in chunk} x[b,i] * lut[o, qidx[i,o]]
// DRAM-pattern fix: 1024-thread blocks; thread owns cols bx*4096 + tid*4, so
// each block-level qidx load is a 16 KB CONTIGUOUS span (vs 4 KB stripe with
// 28 KB skips), and only 2 co-resident blocks interleave per 2 MB region.
// grid = (2, NSPLIT) = 256 blocks = 1 block/CU (16 waves, 4/SIMD).
// launch_bounds(1024,4) caps VGPR at 128 (est ~106 live).
__global__ __launch_bounds__(1024, 4) void dense_kernel(const int* __restrict__ qidx,
                                                        const float* __restrict__ lut,
                                                        const float* __restrict__ xT,
                                                        float* __restrict__ P) {
    __shared__ float4 xs[CHUNK][2];    // xs[ii] = {x[0..3][i0+ii], x[4..7][i0+ii]}

    const int tid = threadIdx.x;
    const int col0 = blockIdx.x * (O_F / 2) + tid * 4;
    const int i0 = blockIdx.y * CHUNK;

    // Stage x-chunk: CHUNK*2 = 128 float4s, coalesced.
    if (tid < CHUNK * 2)
        ((float4*)xs)[tid] = ((const float4*)(xT + (size_t)i0 * 8))[tid];

    // Preload the 4 columns' LUT rows: 8 f32 each -> 2 float4 regs/col.
    float4 lA[4], lB[4];
#pragma unroll
    for (int c = 0; c < 4; ++c) {
        const float4* p = (const float4*)(lut + (size_t)(col0 + c) * 8);
        lA[c] = p[0];
        lB[c] = p[1];
    }

    float acc[4][8];
#pragma unroll
    for (int c = 0; c < 4; ++c)
#pragma unroll
        for (int b = 0; b < 8; ++b) acc[c][b] = 0.0f;

    __syncthreads();

    const int4* qp = (const int4*)(qidx + (size_t)i0 * O_F + col0);

    for (int t = 0; t < CHUNK; t += QBATCH) {
        // Phase A: issue QBATCH loads into a static register array.
        int4 qb[QBATCH];
#pragma unroll
        for (int k = 0; k < QBATCH; ++k)
            qb[k] = qp[(size_t)(t + k) * (O_F / 4)];

        // Phase B: consume.
#pragma unroll
        for (int k = 0; k < QBATCH; ++k) {
            const int4   q   = qb[k];
            const float4 xlo = xs[t + k][0];   // LDS broadcast
            const float4 xhi = xs[t + k][1];
#pragma unroll
            for (int c = 0; c < 4; ++c) {
                const int qc = (c == 0) ? q.x : (c == 1) ? q.y : (c == 2) ? q.z : q.w;
                const float w = lut_sel(lA[c], lB[c], qc);
                acc[c][0] += xlo.x * w;
                acc[c][1] += xlo.y * w;
                acc[c][2] += xlo.z * w;
                acc[c][3] += xlo.w * w;
                acc[c][4] += xhi.x * w;
                acc[c][5] += xhi.y * w;
                acc[c][6] += xhi.z * w;
                acc[c][7] += xhi.w * w;
            }
        }
    }

    // P layout: [split][b][O_F]; per b one float4 covering the 4 owned cols
    // (1024 threads -> 16 KB contiguous store per b).
    float* Pb = P + ((size_t)blockIdx.y * 8) * O_F + col0;
#pragma unroll
    for (int b = 0; b < 8; ++b) {
        float4 v = make_float4(acc[0][b], acc[1][b], acc[2][b], acc[3][b]);
        *(float4*)(Pb + (size_t)b * O_F) = v;
    }
}

// Sparse: one wave per output row o; 128 nnz -> 2 per lane; gather from
// L2-resident xT; butterfly-reduce; lane 0 stores 8 values to sp. NO atomics.
__global__ __launch_bounds__(256) void sparse_kernel(const int* __restrict__ rows,
                                                     const int* __restrict__ cols,
                                                     const float* __restrict__ vals,
                                                     const float* __restrict__ xT,
                                                     float* __restrict__ sp) {
    const int wave = threadIdx.x >> 6;
    const int lane = threadIdx.x & 63;
    const int o = blockIdx.x * 4 + wave;
    const int r0 = rows[o];
    const int r1 = rows[o + 1];

    float acc[8];
#pragma unroll
    for (int b = 0; b < 8; ++b) acc[b] = 0.0f;

    for (int k = r0 + lane; k < r1; k += 64) {
        const int   col = cols[k];
        const float v   = vals[k];
        const float4* xp = (const float4*)(xT + (size_t)col * 8);
        const float4 xlo = xp[0];
        const float4 xhi = xp[1];
        acc[0] += v * xlo.x;
        acc[1] += v * xlo.y;
        acc[2] += v * xlo.z;
        acc[3] += v * xlo.w;
        acc[4] += v * xhi.x;
        acc[5] += v * xhi.y;
        acc[6] += v * xhi.z;
        acc[7] += v * xhi.w;
    }

#pragma unroll
    for (int s = 1; s < 64; s <<= 1)
#pragma unroll
        for (int b = 0; b < 8; ++b) acc[b] += __shfl_xor(acc[b], s, 64);

    if (lane == 0) {
#pragma unroll
        for (int b = 0; b < 8; ++b) sp[(size_t)b * O_F + o] = acc[b];
    }
}

// out[t] = sp[t] + sum_s P[s][t]  (t over 8*O_F elems, float4-vectorized).
// grid = 256 x 64 (one wave per CU; unroll-8 keeps 8 KB/wave in flight).
__global__ __launch_bounds__(64) void reduce_kernel(const float* __restrict__ P,
                                                    const float* __restrict__ sp,
                                                    float* __restrict__ out) {
    const int t4 = blockIdx.x * 64 + threadIdx.x;   // 0..16383 (float4 units)
    float4 s = ((const float4*)sp)[t4];
#pragma unroll 8
    for (int k = 0; k < NSPLIT; ++k) {
        const float4 p = ((const float4*)P)[(size_t)k * (8 * O_F / 4) + t4];
        s.x += p.x; s.y += p.y; s.z += p.z; s.w += p.w;
    }
    ((float4*)out)[t4] = s;
}

extern "C" void kernel_launch(void* const* d_in, const int* in_sizes, int n_in,
                              void* d_out, int out_size, void* d_ws, size_t ws_size,
                              hipStream_t stream) {
    const float* x    = (const float*)d_in[0];
    const int*   qidx = (const int*)d_in[1];
    const float* lut  = (const float*)d_in[2];
    const int*   rows = (const int*)d_in[3];
    const int*   cols = (const int*)d_in[4];
    const float* vals = (const float*)d_in[5];
    float* out = (float*)d_out;

    // Workspace layout: xT (256 KB) | sp (256 KB) | P (NSPLIT * 256 KB = 32 MB)
    float* xT = (float*)d_ws;
    float* sp = xT + (size_t)I_F * 8;
    float* P  = sp + (size_t)O_F * 8;

    prolog_kernel<<<I_F / 256, 256, 0, stream>>>(x, xT);
    dense_kernel<<<dim3(2, NSPLIT), 1024, 0, stream>>>(qidx, lut, xT, P);
    sparse_kernel<<<O_F / 4, 256, 0, stream>>>(rows, cols, vals, xT, sp);
    reduce_kernel<<<(8 * O_F / 4) / 64, 64, 0, stream>>>(P, sp, out);
}